// Round 9
// baseline (3207.151 us; speedup 1.0000x reference)
//
#include <hip/hip_runtime.h>
#include <hip/hip_bf16.h>
#include <stdint.h>

// ---------------------------------------------------------------------------
// NaiveLSTM: B=64, T=1024, I=512, H=512
//   phase 0: convert x->bf16; transpose W,U; init hist (slot0 = h0 = 0,
//            slots 1..1024 = bf16-NaN sentinel)
//   phase 1: xW = x @ W  (bf16 MFMA GEMM, global_load_lds staging)
//   phase 2: sequential LSTM (R8 skeleton + 3 fixes):
//     - U fragments loaded via asm (non-rematerializable) -> truly resident
//       in 128 VGPRs; kills the 128KB/block/step L2 re-feed R8 was paying.
//     - raw barrier (lgkmcnt-only drain) -> vmem never drained at barrier.
//     - xW(t+1) issued post-poll-detect -> poll vmcnt(0) no longer eats
//       cold-HBM xW latency. 4 independent MFMA chains of 8.
// ---------------------------------------------------------------------------

typedef __attribute__((ext_vector_type(8))) short bf16x8;
typedef __attribute__((ext_vector_type(4))) float f32x4;

constexpr int T_STEPS = 1024;
constexpr int HS = 512;
constexpr int NGROUP = 4;                       // batch groups, 16 rows each
constexpr unsigned SENT = 0x7FC07FC0u;          // bf16 NaN pair; h finite always
constexpr int HIST_SLOT_U32 = 16 * 512 / 2;     // 4096 u32 = 16KB per step/group

__device__ __forceinline__ unsigned short f2bf(float f) {
  unsigned u = __float_as_uint(f);
  u += 0x7fffu + ((u >> 16) & 1u);              // RNE
  return (unsigned short)(u >> 16);
}
__device__ __forceinline__ float bf_lo(unsigned u) { return __uint_as_float(u << 16); }
__device__ __forceinline__ float bf_hi(unsigned u) { return __uint_as_float(u & 0xffff0000u); }

__device__ __forceinline__ float fast_sig(float x) {
  return __builtin_amdgcn_rcpf(1.f + __expf(-x));
}
__device__ __forceinline__ float fast_tanh(float x) {
  return 2.f * __builtin_amdgcn_rcpf(1.f + __expf(-2.f * x)) - 1.f;
}

// ----- system-scope (LLC, cross-XCD safe) ops — proven rounds 1-8 -----
__device__ __forceinline__ void stg_u32_llc(void* p, unsigned v) {
  asm volatile("global_store_dword %0, %1, off sc0 sc1" :: "v"(p), "v"(v) : "memory");
}
__device__ __forceinline__ void ldg_64B_llc(const void* p, uint4& a, uint4& b, uint4& c, uint4& d) {
  const char* q = (const char*)p;
  asm volatile(
      "global_load_dwordx4 %0, %4, off sc0 sc1\n\t"
      "global_load_dwordx4 %1, %5, off sc0 sc1\n\t"
      "global_load_dwordx4 %2, %6, off sc0 sc1\n\t"
      "global_load_dwordx4 %3, %7, off sc0 sc1\n\t"
      "s_waitcnt vmcnt(0)"
      : "=&v"(a), "=&v"(b), "=&v"(c), "=&v"(d)
      : "v"(q), "v"(q + 16), "v"(q + 32), "v"(q + 48)
      : "memory");
}
// asm-defined load: result is NOT rematerializable -> RA must keep it resident
#define LDU(dst, addr) \
  asm volatile("global_load_dwordx4 %0, %1, off" : "=v"(dst) : "v"(addr) : "memory")

// raw barrier: drain LDS ops only (NOT vmem) then s_barrier
__device__ __forceinline__ void bar_lds() {
  asm volatile("s_waitcnt lgkmcnt(0)" ::: "memory");
  __builtin_amdgcn_s_barrier();
}

// ---------------------------------------------------------------------------
__global__ __launch_bounds__(256) void conv_f32_to_bf16(const float* __restrict__ in,
                                                        uint4* __restrict__ out, int n16) {
  int i = blockIdx.x * 256 + threadIdx.x;
  const int stride = gridDim.x * 256;
  for (; i < n16; i += stride) {
    float4 a = ((const float4*)in)[2 * i];
    float4 b = ((const float4*)in)[2 * i + 1];
    uint4 o;
    o.x = (unsigned)f2bf(a.x) | ((unsigned)f2bf(a.y) << 16);
    o.y = (unsigned)f2bf(a.z) | ((unsigned)f2bf(a.w) << 16);
    o.z = (unsigned)f2bf(b.x) | ((unsigned)f2bf(b.y) << 16);
    o.w = (unsigned)f2bf(b.z) | ((unsigned)f2bf(b.w) << 16);
    out[i] = o;
  }
}

// ---------------------------------------------------------------------------
__global__ __launch_bounds__(256) void transpose_to_bf16(const float* __restrict__ in,
                                                         unsigned short* __restrict__ out,
                                                         int R, int C) {
  __shared__ unsigned short tile[64][72];
  const int tx = threadIdx.x & 63, ty = threadIdx.x >> 6;
  const int c0 = blockIdx.x * 64, r0 = blockIdx.y * 64;
#pragma unroll
  for (int rr = ty; rr < 64; rr += 4)
    tile[rr][tx] = f2bf(in[(size_t)(r0 + rr) * C + c0 + tx]);
  __syncthreads();
#pragma unroll
  for (int cc = ty; cc < 64; cc += 4)
    out[(size_t)(c0 + cc) * R + r0 + tx] = tile[tx][cc];
}

// ---------------------------------------------------------------------------
// hist init: per group, slot 0 (h0) = 0.0, slots 1..1024 = sentinel.
// Runs EVERY launch (graph replays reuse the buffer).
// ---------------------------------------------------------------------------
__global__ __launch_bounds__(256) void init_hist(uint4* __restrict__ hist4) {
  const unsigned per_g = 1025u * 1024u;          // uint4 per 16KB-slot group region
  const unsigned total = NGROUP * per_g;
  unsigned i = blockIdx.x * 256 + threadIdx.x;
  const unsigned stride = gridDim.x * 256;
  for (; i < total; i += stride) {
    const unsigned w = i % per_g;
    const unsigned v = (w < 1024u) ? 0u : SENT;  // slot 0 = 1024 uint4
    hist4[i] = make_uint4(v, v, v, v);
  }
}

// ---------------------------------------------------------------------------
// Phase 1 GEMM (unchanged, proven): 128x128 tile, BK=64, global_load_lds.
// ---------------------------------------------------------------------------
__global__ __launch_bounds__(256, 1) void gemm_xw(const unsigned short* __restrict__ A,
                                                  const unsigned short* __restrict__ Bt,
                                                  unsigned short* __restrict__ C) {
  __shared__ __align__(16) char Al[128 * 128];
  __shared__ __align__(16) char Bl[128 * 128];
  const int tid = threadIdx.x, lane = tid & 63, wave = tid >> 6;
  const int n0 = blockIdx.x * 128;
  const size_t m0 = (size_t)blockIdx.y * 128;
  const int wm = wave >> 1, wn = wave & 1;
  f32x4 acc[4][4] = {};

  for (int ks = 0; ks < 8; ++ks) {
    const int k0 = ks * 64;
    if (ks) __syncthreads();
#pragma unroll
    for (int p = 0; p < 4; ++p) {
      const int off = p * 4096 + wave * 1024 + lane * 16;
      const int row = off >> 7, kb = off & 127;
      const unsigned short* ga = A + (m0 + row) * 512 + k0 + (kb >> 1);
      const unsigned short* gb = Bt + (size_t)(n0 + row) * 512 + k0 + (kb >> 1);
      __builtin_amdgcn_global_load_lds(
          (const __attribute__((address_space(1))) void*)ga,
          (__attribute__((address_space(3))) void*)(Al + p * 4096 + wave * 1024), 16, 0, 0);
      __builtin_amdgcn_global_load_lds(
          (const __attribute__((address_space(1))) void*)gb,
          (__attribute__((address_space(3))) void*)(Bl + p * 4096 + wave * 1024), 16, 0, 0);
    }
    __syncthreads();
#pragma unroll
    for (int kk = 0; kk < 2; ++kk) {
      const int kb = (kk * 32 + (lane >> 4) * 8) * 2;
      bf16x8 av[4], bv[4];
#pragma unroll
      for (int i = 0; i < 4; ++i)
        av[i] = *(const bf16x8*)(Al + (wm * 64 + i * 16 + (lane & 15)) * 128 + kb);
#pragma unroll
      for (int j = 0; j < 4; ++j)
        bv[j] = *(const bf16x8*)(Bl + (wn * 64 + j * 16 + (lane & 15)) * 128 + kb);
#pragma unroll
      for (int i = 0; i < 4; ++i)
#pragma unroll
        for (int j = 0; j < 4; ++j)
          acc[i][j] = __builtin_amdgcn_mfma_f32_16x16x32_bf16(av[i], bv[j], acc[i][j], 0, 0, 0);
    }
  }
#pragma unroll
  for (int i = 0; i < 4; ++i)
#pragma unroll
    for (int j = 0; j < 4; ++j) {
      const int col = n0 + wn * 64 + j * 16 + (lane & 15);
#pragma unroll
      for (int r = 0; r < 4; ++r) {
        const int row = wm * 64 + i * 16 + (lane >> 4) * 4 + r;
        C[(m0 + row) * (size_t)2048 + col] = f2bf(acc[i][j][r]);
      }
    }
}

// ---------------------------------------------------------------------------
// Phase 2: sequential LSTM. 64 blocks x 256 threads (4 waves).
// group g = bid&3 (rows g*16..+16), bg = bid>>2 owns h-cols [bg*32, +32).
// Wave w owns 8 cols [C0, C0+8), C0 = bg*32 + w*8. Lane-local gate layout
// (R8, verified): D = mfma(A=U-frag rows (colpair,gate), B=h-frag) ->
// lane (b=lane&15, q=lane>>4) holds all 4 gates of cells (b, C0+2q+{0,1}).
// Per step: poll (only poll loads outstanding) -> issue xW(t+1) -> stage ->
// raw barrier (lgkm only) -> 4 MFMA chains of 8 (U resident in VGPRs) ->
// elementwise -> publish u32 (sc1) -> fp32 out (lazy).
// ---------------------------------------------------------------------------
__global__ __launch_bounds__(256, 1) void lstm_seq(const unsigned* __restrict__ xW,       // bf16 pairs [65536][1024]
                                                   const unsigned short* __restrict__ Ut, // bf16 [2048][512]
                                                   const float* __restrict__ bias,        // [2048]
                                                   float* __restrict__ out,
                                                   unsigned* __restrict__ hist) {
  __shared__ __align__(16) unsigned short hl[2][16 * 512];  // dbuf, 32KB

  const int tid = threadIdx.x, lane = tid & 63, wave = tid >> 6;
  const int g = blockIdx.x & 3;
  const int bg = blockIdx.x >> 2;
  const int C0 = bg * 32 + wave * 8;
  const int bm0 = g * 16;

  // A-side (U-frag) roles
  const int r16 = lane & 15;            // A row within the 16
  const int gate_a = r16 & 3;           // gate of this A row
  const int cp_a = r16 >> 2;            // col-pair of this A row
  const int kq = lane >> 4;             // k-chunk id
  // D-side (output) roles
  const int b = lane & 15;              // batch row (in group)
  const int q = lane >> 4;              // col-pair id
  const int colA = C0 + 2 * q;          // output cols colA, colA+1
  const int bglob = bm0 + b;

  // ---- one-time: U fragments via asm loads -> NON-rematerializable, so RA
  //      keeps all 128 VGPRs resident across the whole t-loop (R8's reload
  //      of 128KB/step from L2 eliminated) ----
  bf16x8 uf1[16], uf2[16];
  {
    const unsigned short* ua = Ut + (size_t)(gate_a * 512 + C0 + 2 * cp_a) * 512 + kq * 8;
#pragma unroll
    for (int ks = 0; ks < 16; ++ks) {
      LDU(uf1[ks], ua + ks * 32);
      LDU(uf2[ks], ua + 512 + ks * 32);   // col +1 -> one U row down
    }
    asm volatile("s_waitcnt vmcnt(0)" ::: "memory");
  }

  float biasA[4], biasB[4];
#pragma unroll
  for (int r = 0; r < 4; ++r) {
    biasA[r] = bias[r * 512 + colA];
    biasB[r] = bias[r * 512 + colA + 1];
  }
  float cA = 0.f, cB = 0.f;             // cell state, lane-local

  // h B-frag read (from hl, swizzled): row = lane&15, k-chunk kq
  const int am = lane & 15;
  const int asw = (am & 7) << 4;
  const int kgb = kq * 16;
  // stage roles (thread tid stages 64B of row tid>>4)
  const int rowb = (tid >> 4) * 1024;
  const int colb = (tid & 15) * 64;
  const int sw = ((tid >> 4) & 7) << 4;

  // prologue: xW(0)
  unsigned xwv[4];
  {
    const unsigned* base = xW + (size_t)(bglob * T_STEPS) * 1024;
#pragma unroll
    for (int r = 0; r < 4; ++r) xwv[r] = base[r * 256 + (colA >> 1)];
  }

  __syncthreads();

  for (int t = 0; t < T_STEPS; ++t) {
    // ---- poll h_t data (sentinel; ONLY poll loads pending -> pure LLC RT;
    //      previous step's stores/loads are >1 step old and retired) ----
    uint4 pa, pb, pc, pd;
    {
      const char* hb = (const char*)hist + (size_t)(g * 1025 + t) * 16384 + tid * 64;
      for (;;) {
        ldg_64B_llc(hb, pa, pb, pc, pd);
        const bool bad = (pa.x == SENT) | (pa.y == SENT) | (pa.z == SENT) | (pa.w == SENT) |
                         (pb.x == SENT) | (pb.y == SENT) | (pb.z == SENT) | (pb.w == SENT) |
                         (pc.x == SENT) | (pc.y == SENT) | (pc.z == SENT) | (pc.w == SENT) |
                         (pd.x == SENT) | (pd.y == SENT) | (pd.z == SENT) | (pd.w == SENT);
        if (!bad) break;
      }
    }
    // ---- issue xW(t+1) NOW: retires under MFMA/elementwise, never under a
    //      barrier (raw barrier doesn't drain vmem), ~retired by next poll ----
    unsigned xwn[4];
    {
      const int tn = (t + 1 < T_STEPS) ? t + 1 : t;
      const unsigned* basen = xW + (size_t)(bglob * T_STEPS + tn) * 1024;
#pragma unroll
      for (int r = 0; r < 4; ++r) xwn[r] = basen[r * 256 + (colA >> 1)];
    }
    // ---- stage h_t to LDS (swizzled), double-buffered ----
    {
      char* dst = (char*)hl[t & 1];
      *(uint4*)(dst + ((rowb + colb) ^ sw)) = pa;
      *(uint4*)(dst + ((rowb + colb + 16) ^ sw)) = pb;
      *(uint4*)(dst + ((rowb + colb + 32) ^ sw)) = pc;
      *(uint4*)(dst + ((rowb + colb + 48) ^ sw)) = pd;
    }
    bar_lds();  // lgkmcnt(0) + s_barrier — vmem stays in flight

    // ---- acc init = bias + xW(t); 4 independent MFMA chains of 8 ----
    f32x4 a1, a2, b1 = {0.f, 0.f, 0.f, 0.f}, b2 = {0.f, 0.f, 0.f, 0.f};
#pragma unroll
    for (int r = 0; r < 4; ++r) {
      a1[r] = biasA[r] + bf_lo(xwv[r]);
      a2[r] = biasB[r] + bf_hi(xwv[r]);
    }
    const char* hbase = (const char*)hl[t & 1];
#pragma unroll
    for (int ks = 0; ks < 16; ks += 2) {
      const bf16x8 h0 = *(const bf16x8*)(hbase + ((am * 1024 + ks * 64 + kgb) ^ asw));
      const bf16x8 h1 = *(const bf16x8*)(hbase + ((am * 1024 + (ks + 1) * 64 + kgb) ^ asw));
      a1 = __builtin_amdgcn_mfma_f32_16x16x32_bf16(uf1[ks], h0, a1, 0, 0, 0);
      a2 = __builtin_amdgcn_mfma_f32_16x16x32_bf16(uf2[ks], h0, a2, 0, 0, 0);
      b1 = __builtin_amdgcn_mfma_f32_16x16x32_bf16(uf1[ks + 1], h1, b1, 0, 0, 0);
      b2 = __builtin_amdgcn_mfma_f32_16x16x32_bf16(uf2[ks + 1], h1, b2, 0, 0, 0);
    }
    const f32x4 acc1 = a1 + b1, acc2 = a2 + b2;

    // ---- lane-local elementwise: 2 cells (b, colA), (b, colA+1) ----
    const float iA = fast_sig(acc1[0]), fA = fast_sig(acc1[1]);
    const float gA = fast_tanh(acc1[2]), oA = fast_sig(acc1[3]);
    cA = fA * cA + iA * gA;
    const float hA = oA * fast_tanh(cA);
    const float iB = fast_sig(acc2[0]), fB = fast_sig(acc2[1]);
    const float gB = fast_tanh(acc2[2]), oB = fast_sig(acc2[3]);
    cB = fB * cB + iB * gB;
    const float hB = oB * fast_tanh(cB);

    // ---- publish h_{t+1} FIRST (one u32, system scope) ----
    const unsigned hp = (unsigned)f2bf(hA) | ((unsigned)f2bf(hB) << 16);
    stg_u32_llc(hist + (size_t)(g * 1025 + t + 1) * HIST_SLOT_U32 + b * 256 + (colA >> 1), hp);
    // ---- fp32 hidden_seq (retires lazily) ----
    *(float2*)(out + ((size_t)bglob * T_STEPS + t) * HS + colA) = make_float2(hA, hB);
    if (t == T_STEPS - 1) {
      const size_t hs_total = (size_t)64 * T_STEPS * HS;
      *(float2*)(out + hs_total + (size_t)bglob * HS + colA) = make_float2(hA, hB);
      *(float2*)(out + hs_total + 64 * HS + (size_t)bglob * HS + colA) = make_float2(cA, cB);
    }
#pragma unroll
    for (int r = 0; r < 4; ++r) xwv[r] = xwn[r];
    // no second barrier: hl dbuf; stage(t+2) is gated by poll(t+2) which
    // requires publishes(t+1), which require every wave's MFMA(t) reads done
  }
}

// ---------------------------------------------------------------------------
extern "C" void kernel_launch(void* const* d_in, const int* in_sizes, int n_in,
                              void* d_out, int out_size, void* d_ws, size_t ws_size,
                              hipStream_t stream) {
  const float* x = (const float*)d_in[0];
  const float* W = (const float*)d_in[1];
  const float* U = (const float*)d_in[2];
  const float* bias = (const float*)d_in[3];
  float* out = (float*)d_out;
  char* ws = (char*)d_ws;

  size_t off = 0;
  unsigned short* x_bf = (unsigned short*)(ws + off); off += (size_t)65536 * 512 * 2;        // 64MB
  unsigned short* Wt = (unsigned short*)(ws + off);   off += (size_t)2048 * 512 * 2;         // 2MB
  unsigned short* Ut = (unsigned short*)(ws + off);   off += (size_t)2048 * 512 * 2;         // 2MB
  unsigned* hist = (unsigned*)(ws + off);             off += (size_t)NGROUP * 1025 * 16384;  // 67MB
  unsigned short* xWb = (unsigned short*)(ws + off);  off += (size_t)65536 * 2048 * 2;       // 256MB
  if (ws_size < off) return;

  conv_f32_to_bf16<<<4096, 256, 0, stream>>>(x, (uint4*)x_bf, 33554432 / 8);
  transpose_to_bf16<<<dim3(32, 8), 256, 0, stream>>>(W, Wt, 512, 2048);
  transpose_to_bf16<<<dim3(32, 8), 256, 0, stream>>>(U, Ut, 512, 2048);
  init_hist<<<2048, 256, 0, stream>>>((uint4*)hist);
  gemm_xw<<<dim3(16, 512), 256, 0, stream>>>(x_bf, Wt, xWb);
  lstm_seq<<<64, 256, 0, stream>>>((const unsigned*)xWb, Ut, bias, out, hist);
}